// Round 3
// baseline (912.761 us; speedup 1.0000x reference)
//
#include <hip/hip_runtime.h>
#include <hip/hip_fp16.h>
#include <hip/hip_cooperative_groups.h>

namespace cg = cooperative_groups;

#define ND 25000
#define NG 20000
#define NTOT (ND + NG)      // 45000
#define NBLK 128            // hist/fill slices PER NODE TYPE
#define NSB 176             // scan blocks: ceil(45000/256)
#define NBD 391             // ceil(ND/64) gemm tiles, disease
#define NBG 313             // ceil(NG/64) gemm tiles, gene
#define NBT (NBD + NBG)     // 704

typedef _Float16 half8 __attribute__((ext_vector_type(8)));
typedef float f32x4 __attribute__((ext_vector_type(4)));
typedef float f32x2 __attribute__((ext_vector_type(2)));

// ---- workspace layout (bytes), 256B-aligned ----
#define OFF_CNT    0ull           // NSB u32 lookback flags
#define OFF_ROW    180224ull      // NTOT+1 int
#define OFF_PARTD  360704ull      // NBLK*ND u16
#define OFF_PARTG  6760704ull     // NBLK*NG u16
#define OFF_COL    11880704ull    // 2*NE u16
#define OFF_WSW    15880704ull    // 8*128*128 half
#define OFF_XDH    16142848ull    // ND*128 half
#define OFF_XGH    22542848ull    // NG*128 half
#define OFF_X8D    27662848ull    // ND*128 fp8
#define OFF_X8G    30862848ull    // NG*128 fp8
#define OFF_MDH    33422848ull    // ND*128 half
#define OFF_MGH    39822848ull    // NG*128 half
#define OFF_D1H    44942848ull    // ND*128 half
#define OFF_G1H    51342848ull    // NG*128 half
#define OFF_D18    56462848ull    // ND*128 fp8
#define OFF_G18    59662848ull    // NG*128 fp8

struct PrepP {
    const float *xd, *xg;
    __half *ydh, *ygh;
    unsigned char *y8d, *y8g;
    const float* w[8];
    _Float16* wsw;
    const int *src, *dst;
    unsigned short *partD, *partG;
    unsigned int* flags;
    int* row;
    unsigned short* col;
    int E;
};

struct MainP {
    const unsigned char *x8d, *x8g;
    unsigned char *d18, *g18;
    const __half *xdh, *xgh;
    __half *mdh, *mgh, *d1h, *g1h;
    const _Float16* wsw;
    const float *b1dg, *b1gd, *b2dg, *b2gd;
    float* out;
    const int* row;
    const unsigned short* col;
};

// ================= phase bodies (shared by coop + fallback kernels) =================

__device__ void phase_hist_prep(const PrepP& p, unsigned int* h) {
    int bx = blockIdx.x, t = threadIdx.x;
    if (bx < 2 * NBLK) {                  // ---- privatized histogram ----
        bool isD = bx < NBLK;
        int bb = isD ? bx : bx - NBLK;
        const int* key = isD ? p.src : p.dst;
        int nw = isD ? (ND / 2) : (NG / 2);
        for (int i = t; i < nw; i += 256) h[i] = 0;
        __syncthreads();
        int e0 = (int)(((long long)p.E * bb) / NBLK);
        int e1 = (int)(((long long)p.E * (bb + 1)) / NBLK);
        for (int e = e0 + t; e < e1; e += 256) {
            int k = key[e];
            atomicAdd(&h[k >> 1], 1u << ((k & 1) * 16));
        }
        __syncthreads();
        unsigned int* po = (unsigned int*)((isD ? p.partD : p.partG) + (size_t)bb * (isD ? ND : NG));
        for (int i = t; i < nw; i += 256) po[i] = h[i];
    } else {                              // ---- prep: convert + swizzle + flag-zero ----
        int pb = bx - 2 * NBLK;
        int ncb = gridDim.x - 2 * NBLK;   // convert blocks available (dynamic)
        if (pb < 8) {   // W swizzle: slot=(ntile*4+kc)*64+lane
            const float* W = p.w[pb];
            _Float16* o = p.wsw + (size_t)pb * 16384;
            for (int rep = 0; rep < 8; ++rep) {
                int slot = rep * 256 + t;
                int lane = slot & 63, grp = slot >> 6;
                int kc = grp & 3, ntile = grp >> 2;
                int nn = ntile * 16 + (lane & 15);
                int kb = kc * 32 + (lane >> 4) * 8;
                half8 v;
#pragma unroll
                for (int j = 0; j < 8; ++j) v[j] = (_Float16)W[(size_t)(kb + j) * 128 + nn];
                *(half8*)(o + (size_t)slot * 8) = v;
            }
        } else if (pb == 8 && t < NSB) {  // zero lookback flags for scan phase
            p.flags[t] = 0u;
        }
        const int ndq = ND * 32;
        const int tot = ndq + NG * 32;
        for (int i = pb * 256 + t; i < tot; i += ncb * 256) {
            const float* x; __half* y; unsigned char* y8; int idx;
            if (i < ndq) { x = p.xd; y = p.ydh; y8 = p.y8d; idx = i; }
            else         { x = p.xg; y = p.ygh; y8 = p.y8g; idx = i - ndq; }
            float4 v = ((const float4*)x)[idx];
            ((__half2*)y)[idx * 2 + 0] = __floats2half2_rn(v.x, v.y);
            ((__half2*)y)[idx * 2 + 1] = __floats2half2_rn(v.z, v.w);
            int p8 = __builtin_amdgcn_cvt_pk_fp8_f32(v.x, v.y, 0, false);
            p8 = __builtin_amdgcn_cvt_pk_fp8_f32(v.z, v.w, p8, true);
            ((int*)y8)[idx] = p8;
        }
    }
}

__device__ void phase_scan(const PrepP& p, int* sd, int* sbase_p) {
    int t = threadIdx.x, bid = blockIdx.x;    // bid < NSB
    int k = bid * 256 + t;
    int run = 0;
    if (k < NTOT) {                       // per-key scan over NBLK partial slices
        unsigned short* part;
        int nb, kk;
        if (k < ND) { part = p.partD; nb = ND; kk = k; }
        else        { part = p.partG; nb = NG; kk = k - ND; }
#pragma unroll 8
        for (int b = 0; b < NBLK; ++b) {
            size_t idx = (size_t)b * nb + kk;
            int v = part[idx];
            part[idx] = (unsigned short)run;
            run += v;
        }
    }
    int tsum = run;
    sd[t] = tsum;
    __syncthreads();
    for (int off = 1; off < 256; off <<= 1) {
        int x = (t >= off) ? sd[t - off] : 0;
        __syncthreads();
        sd[t] += x;
        __syncthreads();
    }
    if (t == 0) {                         // publish block aggregate (+1 so 0 == not-ready)
        unsigned int agg = (unsigned int)sd[255] + 1u;
        __hip_atomic_store(&p.flags[bid], agg, __ATOMIC_RELEASE, __HIP_MEMORY_SCOPE_AGENT);
    }
    if (t < 64) {                         // parallel lookback over predecessors
        int s = 0;
        for (int i = t; i < bid; i += 64) {
            unsigned int v;
            do {
                v = __hip_atomic_load(&p.flags[i], __ATOMIC_ACQUIRE, __HIP_MEMORY_SCOPE_AGENT);
            } while (v == 0u);
            s += (int)v - 1;
        }
#pragma unroll
        for (int off = 1; off < 64; off <<= 1) s += __shfl_xor(s, off, 64);
        if (t == 0) *sbase_p = s;
    }
    __syncthreads();
    int base = *sbase_p;
    if (k < NTOT) p.row[k] = base + sd[t] - tsum;
    if (bid == 0 && t == 0) p.row[NTOT] = 2 * p.E;
}

__device__ void phase_fill(const PrepP& p, unsigned int* h) {
    int t = threadIdx.x, b = blockIdx.x;  // b < 2*NBLK
    bool isD = b < NBLK;
    int bb = isD ? b : b - NBLK;
    const int* key = isD ? p.src : p.dst;
    const int* val = isD ? p.dst : p.src;
    const int* rowp = isD ? p.row : p.row + ND;
    int nw = isD ? (ND / 2) : (NG / 2);
    const unsigned int* pi =
        (const unsigned int*)((isD ? p.partD : p.partG) + (size_t)bb * (isD ? ND : NG));
    for (int i = t; i < nw; i += 256) h[i] = pi[i];
    __syncthreads();
    int e0 = (int)(((long long)p.E * bb) / NBLK);
    int e1 = (int)(((long long)p.E * (bb + 1)) / NBLK);
    for (int e = e0 + t; e < e1; e += 256) {
        int k = key[e];
        int v = val[e];
        unsigned int old = atomicAdd(&h[k >> 1], 1u << ((k & 1) * 16));
        int rank = (old >> ((k & 1) * 16)) & 0xffff;
        p.col[rowp[k] + rank] = (unsigned short)v;
    }
}

// ---- aggregation: 1 wave per node, 8 lanes x 16B per neighbor row, 2 rows in flight ----
__device__ __forceinline__ void agg_one(const unsigned char* __restrict__ X,
                                        const int* __restrict__ row,
                                        const unsigned short* __restrict__ col,
                                        int node, _Float16* __restrict__ op0, int lane) {
    int b = row[node], e = row[node + 1];
    int g = lane >> 3, f = lane & 7;
    float acc[16];
#pragma unroll
    for (int k = 0; k < 16; ++k) acc[k] = 0.f;
    int j = b + g;
    for (; j + 8 < e; j += 16) {
        int c0 = col[j], c1 = col[j + 8];
        int4 w0 = *(const int4*)(X + (size_t)c0 * 128 + f * 16);
        int4 w1 = *(const int4*)(X + (size_t)c1 * 128 + f * 16);
        const int* wa = (const int*)&w0;
        const int* wb = (const int*)&w1;
#pragma unroll
        for (int q = 0; q < 4; ++q) {
            f32x2 l0 = __builtin_amdgcn_cvt_pk_f32_fp8(wa[q], false);
            f32x2 h0 = __builtin_amdgcn_cvt_pk_f32_fp8(wa[q], true);
            f32x2 l1 = __builtin_amdgcn_cvt_pk_f32_fp8(wb[q], false);
            f32x2 h1 = __builtin_amdgcn_cvt_pk_f32_fp8(wb[q], true);
            acc[q * 4 + 0] += l0[0] + l1[0];
            acc[q * 4 + 1] += l0[1] + l1[1];
            acc[q * 4 + 2] += h0[0] + h1[0];
            acc[q * 4 + 3] += h0[1] + h1[1];
        }
    }
    if (j < e) {
        int c = col[j];
        int4 w = *(const int4*)(X + (size_t)c * 128 + f * 16);
        const int* wa = (const int*)&w;
#pragma unroll
        for (int q = 0; q < 4; ++q) {
            f32x2 l = __builtin_amdgcn_cvt_pk_f32_fp8(wa[q], false);
            f32x2 h = __builtin_amdgcn_cvt_pk_f32_fp8(wa[q], true);
            acc[q * 4 + 0] += l[0];
            acc[q * 4 + 1] += l[1];
            acc[q * 4 + 2] += h[0];
            acc[q * 4 + 3] += h[1];
        }
    }
#pragma unroll
    for (int k = 0; k < 16; ++k) {
        acc[k] += __shfl_xor(acc[k], 8, 64);
        acc[k] += __shfl_xor(acc[k], 16, 64);
        acc[k] += __shfl_xor(acc[k], 32, 64);
    }
    if (g == 0) {
        int deg = e - b;
        float r = 1.0f / (float)(deg > 0 ? deg : 1);
        half8 o0, o1;
#pragma unroll
        for (int k = 0; k < 8; ++k) o0[k] = (_Float16)(acc[k] * r);
#pragma unroll
        for (int k = 0; k < 8; ++k) o1[k] = (_Float16)(acc[8 + k] * r);
        *(half8*)(op0 + f * 16) = o0;
        *(half8*)(op0 + f * 16 + 8) = o1;
    }
}

// XCD-pinned agg phase: xcd<4 -> disease nodes (table Xg), xcd>=4 -> gene nodes (table Xd).
// gridDim.x must be a multiple of 8; wave index (slot,xcd,wid) is bijective over [0, 2*gridDim).
__device__ void aggp(const unsigned char* __restrict__ Xg, const unsigned char* __restrict__ Xd,
                     const int* __restrict__ row, const unsigned short* __restrict__ col,
                     __half* __restrict__ outd, __half* __restrict__ outg) {
    int wid = threadIdx.x >> 6, lane = threadIdx.x & 63;
    int bid = blockIdx.x;
    int xcd = bid & 7, slot = bid >> 3;
    int stride = gridDim.x * 2;
    if (xcd < 4) {
        int widx = (slot * 4 + xcd) * 4 + wid;
        for (int nd = widx; nd < ND; nd += stride)
            agg_one(Xg, row, col, nd, (_Float16*)outd + (size_t)nd * 128, lane);
    } else {
        int widx = (slot * 4 + (xcd - 4)) * 4 + wid;
        for (int gn = widx; gn < NG; gn += stride)
            agg_one(Xd, row, col, ND + gn, (_Float16*)outg + (size_t)gn * 128, lane);
    }
}

// ---- dual MFMA GEMM tile (64 rows x 128 cols), 4 waves -------------------------------
__device__ void gemm_tile(const __half* __restrict__ A1, const __half* __restrict__ A2,
                          const _Float16* __restrict__ W1, const _Float16* __restrict__ W2,
                          const float* __restrict__ bias,
                          float* __restrict__ Yf, __half* __restrict__ Yh,
                          unsigned char* __restrict__ Y8, int n, int b0, int layer) {
    int t = threadIdx.x;
    int wave = t >> 6, lane = t & 63;
    int row0 = b0 * 64 + wave * 16;
    if (row0 >= n) return;
    int m = lane & 15, quad = lane >> 4;
    int arow = row0 + m;
    if (arow >= n) arow = n - 1;
    const _Float16* a1p = (const _Float16*)A1 + (size_t)arow * 128 + quad * 8;
    const _Float16* a2p = (const _Float16*)A2 + (size_t)arow * 128 + quad * 8;
    half8 a1[4], a2[4];
#pragma unroll
    for (int kc = 0; kc < 4; ++kc) {
        a1[kc] = *(const half8*)(a1p + kc * 32);
        a2[kc] = *(const half8*)(a2p + kc * 32);
    }
#pragma unroll
    for (int ntile = 0; ntile < 8; ++ntile) {
        f32x4 acc = {0.f, 0.f, 0.f, 0.f};
#pragma unroll
        for (int kc = 0; kc < 4; ++kc) {
            half8 b1 = *(const half8*)(W1 + (size_t)((ntile * 4 + kc) * 64 + lane) * 8);
            acc = __builtin_amdgcn_mfma_f32_16x16x32_f16(a1[kc], b1, acc, 0, 0, 0);
            half8 b2 = *(const half8*)(W2 + (size_t)((ntile * 4 + kc) * 64 + lane) * 8);
            acc = __builtin_amdgcn_mfma_f32_16x16x32_f16(a2[kc], b2, acc, 0, 0, 0);
        }
        int colx = ntile * 16 + m;
        float bb = bias[colx];
#pragma unroll
        for (int r = 0; r < 4; ++r) {
            int rr = row0 + quad * 4 + r;
            if (rr < n) {
                float v = acc[r] + bb;
                if (layer == 2) {
                    Yf[(size_t)rr * 128 + colx] = v;
                } else {
                    Yh[(size_t)rr * 128 + colx] = __float2half(v);
                    int p8 = __builtin_amdgcn_cvt_pk_fp8_f32(v, v, 0, false);
                    Y8[(size_t)rr * 128 + colx] = (unsigned char)(p8 & 0xff);
                }
            }
        }
    }
}

__device__ void gemm_sel(const MainP& p, int layer) {
    int bx = blockIdx.x;                  // bx < NBT guaranteed by caller
    bool isD = bx < NBD;
    int n = isD ? ND : NG, b0 = isD ? bx : bx - NBD;
    const __half* A1 = isD ? p.mdh : p.mgh;
    const __half* A2;
    const _Float16 *W1, *W2;
    const float* bias;
    float* Yf = nullptr;
    __half* Yh = nullptr;
    unsigned char* Y8 = nullptr;
    if (layer == 1) {
        A2 = isD ? p.xdh : p.xgh;
        W1 = p.wsw + (size_t)(isD ? 2 : 0) * 16384;
        W2 = p.wsw + (size_t)(isD ? 3 : 1) * 16384;
        bias = isD ? p.b1gd : p.b1dg;
        Yh = isD ? p.d1h : p.g1h;
        Y8 = isD ? p.d18 : p.g18;
    } else {
        A2 = isD ? p.d1h : p.g1h;
        W1 = p.wsw + (size_t)(isD ? 6 : 4) * 16384;
        W2 = p.wsw + (size_t)(isD ? 7 : 5) * 16384;
        bias = isD ? p.b2gd : p.b2dg;
        Yf = isD ? p.out : p.out + (size_t)ND * 128;
    }
    gemm_tile(A1, A2, W1, W2, bias, Yf, Yh, Y8, n, b0, layer);
}

// ================= cooperative kernels =================

__global__ __launch_bounds__(256, 3) void csrprep(PrepP p) {
    __shared__ unsigned int h[12544];     // 50176 B (3 blocks/CU)
    __shared__ int sbase;
    cg::grid_group grid = cg::this_grid();
    phase_hist_prep(p, h);
    grid.sync();
    if (blockIdx.x < NSB) phase_scan(p, (int*)h, &sbase);
    grid.sync();
    if (blockIdx.x < 2 * NBLK) phase_fill(p, h);
}

__global__ __launch_bounds__(256, 8) void mainfused(MainP p) {
    cg::grid_group grid = cg::this_grid();
    aggp(p.x8g, p.x8d, p.row, p.col, p.mdh, p.mgh);    // layer-1 aggregate
    grid.sync();
    if (blockIdx.x < NBT) gemm_sel(p, 1);              // layer-1 dual GEMM
    grid.sync();
    aggp(p.g18, p.d18, p.row, p.col, p.mdh, p.mgh);    // layer-2 aggregate
    grid.sync();
    if (blockIdx.x < NBT) gemm_sel(p, 2);              // layer-2 dual GEMM -> out
}

// ================= fallback (7-dispatch) wrappers over the same device code =================

__global__ __launch_bounds__(256) void k_prep(PrepP p) {
    __shared__ unsigned int h[12544];
    phase_hist_prep(p, h);
}
__global__ __launch_bounds__(256) void k_scan(PrepP p) {
    __shared__ int sd[256];
    __shared__ int sbase;
    phase_scan(p, sd, &sbase);
}
__global__ __launch_bounds__(256) void k_fill(PrepP p) {
    __shared__ unsigned int h[12544];
    if (blockIdx.x < 2 * NBLK) phase_fill(p, h);
}
__global__ __launch_bounds__(256, 8) void k_agg(MainP p, int layer) {
    if (layer == 1) aggp(p.x8g, p.x8d, p.row, p.col, p.mdh, p.mgh);
    else            aggp(p.g18, p.d18, p.row, p.col, p.mdh, p.mgh);
}
__global__ __launch_bounds__(256) void k_gemm(MainP p, int layer) {
    if (blockIdx.x < NBT) gemm_sel(p, layer);
}

extern "C" void kernel_launch(void* const* d_in, const int* in_sizes, int n_in,
                              void* d_out, int out_size, void* d_ws, size_t ws_size,
                              hipStream_t stream) {
    const float* x_d = (const float*)d_in[0];
    const float* x_g = (const float*)d_in[1];
    const int*   src = (const int*)d_in[2];
    const int*   dst = (const int*)d_in[3];
    float* out = (float*)d_out;

    char* ws = (char*)d_ws;
    PrepP pp;
    pp.xd = x_d; pp.xg = x_g;
    pp.ydh = (__half*)(ws + OFF_XDH); pp.ygh = (__half*)(ws + OFF_XGH);
    pp.y8d = (unsigned char*)(ws + OFF_X8D); pp.y8g = (unsigned char*)(ws + OFF_X8G);
    pp.w[0] = (const float*)d_in[4];   // w1_dg_l
    pp.w[1] = (const float*)d_in[6];   // w1_dg_r
    pp.w[2] = (const float*)d_in[7];   // w1_gd_l
    pp.w[3] = (const float*)d_in[9];   // w1_gd_r
    pp.w[4] = (const float*)d_in[10];  // w2_dg_l
    pp.w[5] = (const float*)d_in[12];  // w2_dg_r
    pp.w[6] = (const float*)d_in[13];  // w2_gd_l
    pp.w[7] = (const float*)d_in[15];  // w2_gd_r
    pp.wsw = (_Float16*)(ws + OFF_WSW);
    pp.src = src; pp.dst = dst;
    pp.partD = (unsigned short*)(ws + OFF_PARTD);
    pp.partG = (unsigned short*)(ws + OFF_PARTG);
    pp.flags = (unsigned int*)(ws + OFF_CNT);
    pp.row = (int*)(ws + OFF_ROW);
    pp.col = (unsigned short*)(ws + OFF_COL);
    pp.E = in_sizes[2];

    MainP mp;
    mp.x8d = (const unsigned char*)(ws + OFF_X8D);
    mp.x8g = (const unsigned char*)(ws + OFF_X8G);
    mp.d18 = (unsigned char*)(ws + OFF_D18);
    mp.g18 = (unsigned char*)(ws + OFF_G18);
    mp.xdh = (const __half*)(ws + OFF_XDH);
    mp.xgh = (const __half*)(ws + OFF_XGH);
    mp.mdh = (__half*)(ws + OFF_MDH);
    mp.mgh = (__half*)(ws + OFF_MGH);
    mp.d1h = (__half*)(ws + OFF_D1H);
    mp.g1h = (__half*)(ws + OFF_G1H);
    mp.wsw = (const _Float16*)(ws + OFF_WSW);
    mp.b1dg = (const float*)d_in[5];
    mp.b1gd = (const float*)d_in[8];
    mp.b2dg = (const float*)d_in[11];
    mp.b2gd = (const float*)d_in[14];
    mp.out = out;
    mp.row = (const int*)(ws + OFF_ROW);
    mp.col = (const unsigned short*)(ws + OFF_COL);

    // ---- capture-time launch-config resolution (host code runs once under graph capture) ----
    static int coop = -1, gA = 0, gB = 0;
    if (coop < 0) {
        int ca = 0, dev = 0;
        hipGetDevice(&dev);
        hipDeviceGetAttribute(&ca, hipDeviceAttributeCooperativeLaunch, dev);
        if (ca) {
            int mA = 0, mB = 0;
            hipOccupancyMaxActiveBlocksPerMultiprocessor(&mA, csrprep, 256, 0);
            hipOccupancyMaxActiveBlocksPerMultiprocessor(&mB, mainfused, 256, 0);
            hipDeviceProp_t prop;
            hipGetDeviceProperties(&prop, dev);
            int ncu = prop.multiProcessorCount;
            gA = mA * ncu; if (gA > 768) gA = 768;
            gB = (mB * ncu) & ~7; if (gB > 2048) gB = 2048;
            coop = (gA >= 2 * NBLK + 9 && gB >= NBT) ? 1 : 0;
        } else {
            coop = 0;
        }
    }

    if (coop) {
        void* aA[] = { (void*)&pp };
        void* aB[] = { (void*)&mp };
        hipError_t e1 = hipLaunchCooperativeKernel((const void*)csrprep, dim3(gA), dim3(256),
                                                   aA, 0, stream);
        hipError_t e2 = (e1 == hipSuccess)
            ? hipLaunchCooperativeKernel((const void*)mainfused, dim3(gB), dim3(256),
                                         aB, 0, stream)
            : e1;
        if (e1 == hipSuccess && e2 == hipSuccess) return;
        coop = 0;  // fall through to the dispatch chain (idempotent: rebuilds everything)
    }

    // ---- fallback: 7-dispatch chain (identical device code) ----
    k_prep<<<2 * NBLK + 1024, 256, 0, stream>>>(pp);
    k_scan<<<NSB, 256, 0, stream>>>(pp);
    k_fill<<<2 * NBLK, 256, 0, stream>>>(pp);
    k_agg<<<2048, 256, 0, stream>>>(mp, 1);
    k_gemm<<<NBT, 256, 0, stream>>>(mp, 1);
    k_agg<<<2048, 256, 0, stream>>>(mp, 2);
    k_gemm<<<NBT, 256, 0, stream>>>(mp, 2);
}

// Round 4
// 482.201 us; speedup vs baseline: 1.8929x; 1.8929x over previous
//
#include <hip/hip_runtime.h>
#include <hip/hip_fp16.h>

#define ND 25000
#define NG 20000
#define NTOT (ND + NG)      // 45000
#define HB 128              // hist blocks (global-atomic histogram)
#define PREPB 1024          // prep blocks appended after the HB hist blocks
#define NSB 176             // scan chunks: ceil(45000/256)
#define CFB 1024            // csrfin grid (scan + barrier + fill)
#define AGG_SLOTS 1563      // ceil(ceil(ND/4)/4); agg grid = 8*AGG_SLOTS
#define AGG_GRID (8 * AGG_SLOTS)

typedef _Float16 half8 __attribute__((ext_vector_type(8)));
typedef float f32x4 __attribute__((ext_vector_type(4)));
typedef float f32x2 __attribute__((ext_vector_type(2)));

// ---- workspace layout (bytes), 256B-aligned ----
#define OFF_CNT    0ull           // NTOT int degree counters (zeroed each run)
#define OFF_ROW    180224ull      // NTOT+1 int row pointers
#define OFF_FLG    360704ull      // NSB+1 u32: lookback flags + done-counter
#define OFF_POS    361728ull      // NTOT int fill cursors
#define OFF_COL    11880704ull    // 2*NE u16
#define OFF_WSW    15880704ull    // 8*128*128 half
#define OFF_XDH    16142848ull    // ND*128 half
#define OFF_XGH    22542848ull    // NG*128 half
#define OFF_X8D    27662848ull    // ND*128 fp8
#define OFF_X8G    30862848ull    // NG*128 fp8
#define OFF_MDH    33422848ull    // ND*128 half
#define OFF_MGH    39822848ull    // NG*128 half
#define OFF_D1H    44942848ull    // ND*128 half
#define OFF_G1H    51342848ull    // NG*128 half
#define OFF_D18    56462848ull    // ND*128 fp8
#define OFF_G18    59662848ull    // NG*128 fp8  (end ~62.2 MB)

struct WPtrs { const float* w[8]; };

// ---------------- dispatch 0: zero cnt/flags (workspace is re-poisoned every replay) -------------
__global__ __launch_bounds__(256) void zerok(int* __restrict__ cnt,
                                             unsigned int* __restrict__ flags) {
    int i = blockIdx.x * 256 + threadIdx.x;
    for (int k = i; k < NTOT; k += gridDim.x * 256) cnt[k] = 0;
    if (i <= NSB) flags[i] = 0u;
}

// ---------------- dispatch 1: global-atomic hist (blocks 0..HB-1) + prep/convert/swizzle ---------
__global__ __launch_bounds__(256) void prep_hist(const float* __restrict__ xd,
                                                 const float* __restrict__ xg,
                                                 __half* __restrict__ ydh,
                                                 __half* __restrict__ ygh,
                                                 unsigned char* __restrict__ y8d,
                                                 unsigned char* __restrict__ y8g,
                                                 WPtrs wp, _Float16* __restrict__ wsw,
                                                 const int* __restrict__ src,
                                                 const int* __restrict__ dst,
                                                 int* __restrict__ cnt, int E) {
    int bx = blockIdx.x, t = threadIdx.x;
    if (bx < HB) {                        // ---- degree histogram via device atomics ----
        int e0 = (int)(((long long)E * bx) / HB);
        int e1 = (int)(((long long)E * (bx + 1)) / HB);
        for (int e = e0 + t; e < e1; e += 256) {
            atomicAdd(&cnt[src[e]], 1);
            atomicAdd(&cnt[ND + dst[e]], 1);
        }
        return;
    }
    int pb = bx - HB;                     // ---- prep: convert + swizzle ----
    if (pb < 8) {   // W swizzle: slot=(ntile*4+kc)*64+lane; elem j = W[kc*32+(lane>>4)*8+j][ntile*16+(lane&15)]
        const float* W = wp.w[pb];
        _Float16* o = wsw + (size_t)pb * 16384;
        for (int rep = 0; rep < 8; ++rep) {
            int slot = rep * 256 + t;
            int lane = slot & 63, grp = slot >> 6;
            int kc = grp & 3, ntile = grp >> 2;
            int nn = ntile * 16 + (lane & 15);
            int kb = kc * 32 + (lane >> 4) * 8;
            half8 v;
#pragma unroll
            for (int j = 0; j < 8; ++j) v[j] = (_Float16)W[(size_t)(kb + j) * 128 + nn];
            *(half8*)(o + (size_t)slot * 8) = v;
        }
    }
    const int ndq = ND * 32;
    const int tot = ndq + NG * 32;
    for (int i = pb * 256 + t; i < tot; i += PREPB * 256) {
        const float* x;
        __half* y;
        unsigned char* y8;
        int idx;
        if (i < ndq) { x = xd; y = ydh; y8 = y8d; idx = i; }
        else         { x = xg; y = ygh; y8 = y8g; idx = i - ndq; }
        float4 v = ((const float4*)x)[idx];
        ((__half2*)y)[idx * 2 + 0] = __floats2half2_rn(v.x, v.y);
        ((__half2*)y)[idx * 2 + 1] = __floats2half2_rn(v.z, v.w);
        int p8 = __builtin_amdgcn_cvt_pk_fp8_f32(v.x, v.y, 0, false);
        p8 = __builtin_amdgcn_cvt_pk_fp8_f32(v.z, v.w, p8, true);
        ((int*)y8)[idx] = p8;
    }
}

// ---------------- dispatch 2: scan (lookback) + in-kernel barrier + atomic CSR fill --------------
// Blocks 0..NSB-1 scan cnt->row,pos and bump the done-counter (flags[NSB]); all CFB blocks
// spin until done==NSB (all resident: 1KB LDS, low VGPR), then fill col edge-parallel with
// atomicAdd rank cursors. Neighbor order within a row is arbitrary (mean is order-insensitive).
__global__ __launch_bounds__(256) void csrfin(const int* __restrict__ cnt,
                                              int* __restrict__ row,
                                              int* __restrict__ pos,
                                              unsigned int* __restrict__ flags,
                                              const int* __restrict__ src,
                                              const int* __restrict__ dst,
                                              unsigned short* __restrict__ col, int E) {
    __shared__ int sd[256];
    __shared__ int sbase;
    int t = threadIdx.x, bid = blockIdx.x;
    if (bid < NSB) {
        int k = bid * 256 + t;
        int tsum = (k < NTOT) ? cnt[k] : 0;
        sd[t] = tsum;
        __syncthreads();
        for (int off = 1; off < 256; off <<= 1) {
            int x = (t >= off) ? sd[t - off] : 0;
            __syncthreads();
            sd[t] += x;
            __syncthreads();
        }
        if (t == 0) {                     // publish block aggregate (+1 so 0 == not-ready)
            __hip_atomic_store(&flags[bid], (unsigned int)sd[255] + 1u,
                               __ATOMIC_RELEASE, __HIP_MEMORY_SCOPE_AGENT);
        }
        if (t < 64) {                     // parallel lookback over predecessors
            int s = 0;
            for (int i = t; i < bid; i += 64) {
                unsigned int v;
                do {
                    v = __hip_atomic_load(&flags[i], __ATOMIC_ACQUIRE, __HIP_MEMORY_SCOPE_AGENT);
                } while (v == 0u);
                s += (int)v - 1;
            }
#pragma unroll
            for (int off = 1; off < 64; off <<= 1) s += __shfl_xor(s, off, 64);
            if (t == 0) sbase = s;
        }
        __syncthreads();
        if (k < NTOT) {
            int r = sbase + sd[t] - tsum;
            row[k] = r;
            pos[k] = r;
        }
        if (bid == 0 && t == 0) row[NTOT] = 2 * E;
        __syncthreads();
        if (t == 0)                       // scan chunk done (release: row/pos visible)
            __hip_atomic_fetch_add((int*)&flags[NSB], 1,
                                   __ATOMIC_RELEASE, __HIP_MEMORY_SCOPE_AGENT);
    }
    if (t == 0) {                         // barrier: wait for all NSB scan chunks
        while (__hip_atomic_load((int*)&flags[NSB], __ATOMIC_ACQUIRE,
                                 __HIP_MEMORY_SCOPE_AGENT) < NSB)
            __builtin_amdgcn_s_sleep(2);
    }
    __syncthreads();
    for (int i = bid * 256 + t; i < 2 * E; i += CFB * 256) {
        int k, v;
        if (i < E) { k = src[i];            v = dst[i]; }
        else       { int j = i - E; k = ND + dst[j]; v = src[j]; }
        int p = atomicAdd(&pos[k], 1);
        col[p] = (unsigned short)v;
    }
}

// ---------------- dispatches 3/5: fp8 mean aggregation, XCD-pinned -------------------------------
// 1 wave per node, 8 lanes per neighbor row (16 B/lane), 2 rows in flight, f16 out.
// Block->XCD mapping (bid&7): XCDs 0-3 aggregate DISEASE nodes (gather table Xg, 2.56 MB),
// XCDs 4-7 aggregate GENE nodes (gather table Xd, 3.2 MB) -> each table stays L2-resident.
__global__ __launch_bounds__(256, 8) void agg8m(const unsigned char* __restrict__ Xg,
                                                const unsigned char* __restrict__ Xd,
                                                const int* __restrict__ row,
                                                const unsigned short* __restrict__ col,
                                                __half* __restrict__ outd,
                                                __half* __restrict__ outg) {
    int wid = threadIdx.x >> 6, lane = threadIdx.x & 63;
    int bid = blockIdx.x;
    int xcd = bid & 7, slot = bid >> 3;
    const unsigned char* X;
    _Float16* out;
    int node, nloc;
    if (xcd < 4) {                        // disease nodes on XCDs 0-3
        int db = slot * 4 + xcd;
        node = db * 4 + wid;
        if (node >= ND) return;
        X = Xg; out = (_Float16*)outd; nloc = node;
    } else {                              // gene nodes on XCDs 4-7
        int gb = slot * 4 + (xcd - 4);
        int gn = gb * 4 + wid;
        if (gn >= NG) return;
        node = ND + gn;
        X = Xd; out = (_Float16*)outg; nloc = gn;
    }
    int b = row[node], e = row[node + 1];
    int g = lane >> 3, f = lane & 7;
    float acc[16];
#pragma unroll
    for (int k = 0; k < 16; ++k) acc[k] = 0.f;
    int j = b + g;
    for (; j + 8 < e; j += 16) {
        int c0 = col[j], c1 = col[j + 8];
        int4 w0 = *(const int4*)(X + (size_t)c0 * 128 + f * 16);
        int4 w1 = *(const int4*)(X + (size_t)c1 * 128 + f * 16);
        const int* wa = (const int*)&w0;
        const int* wb = (const int*)&w1;
#pragma unroll
        for (int q = 0; q < 4; ++q) {
            f32x2 l0 = __builtin_amdgcn_cvt_pk_f32_fp8(wa[q], false);
            f32x2 h0 = __builtin_amdgcn_cvt_pk_f32_fp8(wa[q], true);
            f32x2 l1 = __builtin_amdgcn_cvt_pk_f32_fp8(wb[q], false);
            f32x2 h1 = __builtin_amdgcn_cvt_pk_f32_fp8(wb[q], true);
            acc[q * 4 + 0] += l0[0] + l1[0];
            acc[q * 4 + 1] += l0[1] + l1[1];
            acc[q * 4 + 2] += h0[0] + h1[0];
            acc[q * 4 + 3] += h0[1] + h1[1];
        }
    }
    if (j < e) {
        int c = col[j];
        int4 w = *(const int4*)(X + (size_t)c * 128 + f * 16);
        const int* wa = (const int*)&w;
#pragma unroll
        for (int q = 0; q < 4; ++q) {
            f32x2 l = __builtin_amdgcn_cvt_pk_f32_fp8(wa[q], false);
            f32x2 h = __builtin_amdgcn_cvt_pk_f32_fp8(wa[q], true);
            acc[q * 4 + 0] += l[0];
            acc[q * 4 + 1] += l[1];
            acc[q * 4 + 2] += h[0];
            acc[q * 4 + 3] += h[1];
        }
    }
#pragma unroll
    for (int k = 0; k < 16; ++k) {
        acc[k] += __shfl_xor(acc[k], 8, 64);
        acc[k] += __shfl_xor(acc[k], 16, 64);
        acc[k] += __shfl_xor(acc[k], 32, 64);
    }
    if (g == 0) {
        int deg = e - b;
        float r = 1.0f / (float)(deg > 0 ? deg : 1);
        half8 o0, o1;
#pragma unroll
        for (int k = 0; k < 8; ++k) o0[k] = (_Float16)(acc[k] * r);
#pragma unroll
        for (int k = 0; k < 8; ++k) o1[k] = (_Float16)(acc[8 + k] * r);
        _Float16* op = out + (size_t)nloc * 128 + f * 16;
        *(half8*)op = o0;
        *(half8*)(op + 8) = o1;
    }
}

// ---------------- dispatches 4/6: merged MFMA dual GEMM ------------------------------------------
struct GemmDual {
    const __half *A1d, *A2d, *A1g, *A2g;
    const _Float16 *W1d, *W2d, *W1g, *W2g;
    const float *biasd, *biasg;
    float *Yfd, *Yfg;
    __half *Yhd, *Yhg;
    unsigned char *Y8d, *Y8g;
};
__global__ __launch_bounds__(256) void gemm2(GemmDual p, int nblkD, int layer) {
    int bx = blockIdx.x;
    bool isD = bx < nblkD;
    const __half* A1 = isD ? p.A1d : p.A1g;
    const __half* A2 = isD ? p.A2d : p.A2g;
    const _Float16* W1 = isD ? p.W1d : p.W1g;
    const _Float16* W2 = isD ? p.W2d : p.W2g;
    const float* bias = isD ? p.biasd : p.biasg;
    float* Yf = isD ? p.Yfd : p.Yfg;
    __half* Yh = isD ? p.Yhd : p.Yhg;
    unsigned char* Y8 = isD ? p.Y8d : p.Y8g;
    int n = isD ? ND : NG, b0 = isD ? bx : bx - nblkD;
    int t = threadIdx.x;
    int wave = t >> 6, lane = t & 63;
    int row0 = b0 * 64 + wave * 16;
    if (row0 >= n) return;
    int m = lane & 15, quad = lane >> 4;
    int arow = row0 + m;
    if (arow >= n) arow = n - 1;
    const _Float16* a1p = (const _Float16*)A1 + (size_t)arow * 128 + quad * 8;
    const _Float16* a2p = (const _Float16*)A2 + (size_t)arow * 128 + quad * 8;
    half8 a1[4], a2[4];
#pragma unroll
    for (int kc = 0; kc < 4; ++kc) {
        a1[kc] = *(const half8*)(a1p + kc * 32);
        a2[kc] = *(const half8*)(a2p + kc * 32);
    }
#pragma unroll
    for (int ntile = 0; ntile < 8; ++ntile) {
        f32x4 acc = {0.f, 0.f, 0.f, 0.f};
#pragma unroll
        for (int kc = 0; kc < 4; ++kc) {
            half8 b1 = *(const half8*)(W1 + (size_t)((ntile * 4 + kc) * 64 + lane) * 8);
            acc = __builtin_amdgcn_mfma_f32_16x16x32_f16(a1[kc], b1, acc, 0, 0, 0);
            half8 b2 = *(const half8*)(W2 + (size_t)((ntile * 4 + kc) * 64 + lane) * 8);
            acc = __builtin_amdgcn_mfma_f32_16x16x32_f16(a2[kc], b2, acc, 0, 0, 0);
        }
        int colx = ntile * 16 + m;
        float bb = bias[colx];
#pragma unroll
        for (int r = 0; r < 4; ++r) {
            int rr = row0 + quad * 4 + r;
            if (rr < n) {
                float v = acc[r] + bb;
                if (layer == 2) {
                    Yf[(size_t)rr * 128 + colx] = v;
                } else {
                    Yh[(size_t)rr * 128 + colx] = __float2half(v);
                    int p8 = __builtin_amdgcn_cvt_pk_fp8_f32(v, v, 0, false);
                    Y8[(size_t)rr * 128 + colx] = (unsigned char)(p8 & 0xff);
                }
            }
        }
    }
}

extern "C" void kernel_launch(void* const* d_in, const int* in_sizes, int n_in,
                              void* d_out, int out_size, void* d_ws, size_t ws_size,
                              hipStream_t stream) {
    const float* x_d = (const float*)d_in[0];
    const float* x_g = (const float*)d_in[1];
    const int*   src = (const int*)d_in[2];
    const int*   dst = (const int*)d_in[3];
    float* out = (float*)d_out;

    char* ws = (char*)d_ws;
    int*            cnt   = (int*)(ws + OFF_CNT);
    int*            row   = (int*)(ws + OFF_ROW);
    unsigned int*   flags = (unsigned int*)(ws + OFF_FLG);
    int*            pos   = (int*)(ws + OFF_POS);
    unsigned short* col   = (unsigned short*)(ws + OFF_COL);
    _Float16*       wsw   = (_Float16*)(ws + OFF_WSW);
    __half*         xd_h  = (__half*)(ws + OFF_XDH);
    __half*         xg_h  = (__half*)(ws + OFF_XGH);
    unsigned char*  x8d   = (unsigned char*)(ws + OFF_X8D);
    unsigned char*  x8g   = (unsigned char*)(ws + OFF_X8G);
    __half*         md_h  = (__half*)(ws + OFF_MDH);
    __half*         mg_h  = (__half*)(ws + OFF_MGH);
    __half*         d1_h  = (__half*)(ws + OFF_D1H);
    __half*         g1_h  = (__half*)(ws + OFF_G1H);
    unsigned char*  d1_8  = (unsigned char*)(ws + OFF_D18);
    unsigned char*  g1_8  = (unsigned char*)(ws + OFF_G18);

    const int E = in_sizes[2];              // 1,000,000
    const int nblkD = (ND + 63) / 64;       // 391
    const int nblkG = (NG + 63) / 64;       // 313

    WPtrs wp;
    wp.w[0] = (const float*)d_in[4];   // w1_dg_l
    wp.w[1] = (const float*)d_in[6];   // w1_dg_r
    wp.w[2] = (const float*)d_in[7];   // w1_gd_l
    wp.w[3] = (const float*)d_in[9];   // w1_gd_r
    wp.w[4] = (const float*)d_in[10];  // w2_dg_l
    wp.w[5] = (const float*)d_in[12];  // w2_dg_r
    wp.w[6] = (const float*)d_in[13];  // w2_gd_l
    wp.w[7] = (const float*)d_in[15];  // w2_gd_r
    const float* b1_dg = (const float*)d_in[5];
    const float* b1_gd = (const float*)d_in[8];
    const float* b2_dg = (const float*)d_in[11];
    const float* b2_gd = (const float*)d_in[14];

    // 0. zero degree counters + lookback flags (workspace re-poisoned each replay)
    zerok<<<64, 256, 0, stream>>>(cnt, flags);
    // 1. global-atomic hist + convert/swizzle (disjoint block ranges)
    prep_hist<<<HB + PREPB, 256, 0, stream>>>(x_d, x_g, xd_h, xg_h, x8d, x8g,
                                              wp, wsw, src, dst, cnt, E);
    // 2. scan -> rowptr, in-kernel barrier, atomic fill
    csrfin<<<CFB, 256, 0, stream>>>(cnt, row, pos, flags, src, dst, col, E);

    // 3-4. layer 1
    agg8m<<<AGG_GRID, 256, 0, stream>>>(x8g, x8d, row, col, md_h, mg_h);
    GemmDual g1p;
    g1p.A1d = md_h; g1p.A2d = xd_h; g1p.W1d = wsw + 2 * 16384; g1p.W2d = wsw + 3 * 16384;
    g1p.biasd = b1_gd; g1p.Yfd = nullptr; g1p.Yhd = d1_h; g1p.Y8d = d1_8;
    g1p.A1g = mg_h; g1p.A2g = xg_h; g1p.W1g = wsw + 0 * 16384; g1p.W2g = wsw + 1 * 16384;
    g1p.biasg = b1_dg; g1p.Yfg = nullptr; g1p.Yhg = g1_h; g1p.Y8g = g1_8;
    gemm2<<<nblkD + nblkG, 256, 0, stream>>>(g1p, nblkD, 1);

    // 5-6. layer 2
    agg8m<<<AGG_GRID, 256, 0, stream>>>(g1_8, d1_8, row, col, md_h, mg_h);
    GemmDual g2p;
    g2p.A1d = md_h; g2p.A2d = d1_h; g2p.W1d = wsw + 6 * 16384; g2p.W2d = wsw + 7 * 16384;
    g2p.biasd = b2_gd; g2p.Yfd = out; g2p.Yhd = nullptr; g2p.Y8d = nullptr;
    g2p.A1g = mg_h; g2p.A2g = g1_h; g2p.W1g = wsw + 4 * 16384; g2p.W2g = wsw + 5 * 16384;
    g2p.biasg = b2_dg; g2p.Yfg = out + (size_t)ND * 128; g2p.Yhg = nullptr; g2p.Y8g = nullptr;
    gemm2<<<nblkD + nblkG, 256, 0, stream>>>(g2p, nblkD, 2);
}

// Round 5
// 253.403 us; speedup vs baseline: 3.6020x; 1.9029x over previous
//
#include <hip/hip_runtime.h>
#include <hip/hip_fp16.h>

#define ND 25000
#define NG 20000
#define NTOT (ND + NG)      // 45000
#define NBLK 128            // hist/fill slices PER NODE TYPE
#define PREPB 1024          // prep blocks appended after the 256 hist blocks
#define NSB 176             // scan blocks: ceil(45000/256)
#define DRNG 6250           // disease nodes per XCD range (ND/4)
#define GRNG 5000           // gene nodes per XCD range (NG/4)
#define AGG_SLOTS 1563      // ceil(DRNG/4); agg grid = 8*AGG_SLOTS
#define AGG_GRID (8 * AGG_SLOTS)

typedef _Float16 half8 __attribute__((ext_vector_type(8)));
typedef float f32x4 __attribute__((ext_vector_type(4)));
typedef float f32x2 __attribute__((ext_vector_type(2)));

// ---- workspace layout (bytes), 256B-aligned ----
#define OFF_CNT    0ull           // NSB u32 lookback flags
#define OFF_ROW    180224ull      // NTOT+1 int
#define OFF_PARTD  360704ull      // NBLK*ND u16
#define OFF_PARTG  6760704ull     // NBLK*NG u16
#define OFF_COL    11880704ull    // 2*NE u16
#define OFF_WSW    15880704ull    // 8*128*128 half
#define OFF_XDH    16142848ull    // ND*128 half
#define OFF_XGH    22542848ull    // NG*128 half
#define OFF_X8D    27662848ull    // ND*128 fp8
#define OFF_X8G    30862848ull    // NG*128 fp8
#define OFF_MDH    33422848ull    // ND*128 half
#define OFF_MGH    39822848ull    // NG*128 half
#define OFF_D1H    44942848ull    // ND*128 half
#define OFF_G1H    51342848ull    // NG*128 half
#define OFF_D18    56462848ull    // ND*128 fp8
#define OFF_G18    59662848ull    // NG*128 fp8  (end ~62.2 MB)

struct WPtrs { const float* w[8]; };

// ---------------- dispatch 1: hist (blocks 0..2*NBLK-1) + prep/convert/swizzle (rest) ------------
__global__ __launch_bounds__(256) void prep_hist(const float* __restrict__ xd,
                                                 const float* __restrict__ xg,
                                                 __half* __restrict__ ydh,
                                                 __half* __restrict__ ygh,
                                                 unsigned char* __restrict__ y8d,
                                                 unsigned char* __restrict__ y8g,
                                                 WPtrs wp, _Float16* __restrict__ wsw,
                                                 const int* __restrict__ src,
                                                 const int* __restrict__ dst,
                                                 unsigned short* __restrict__ partD,
                                                 unsigned short* __restrict__ partG,
                                                 unsigned int* __restrict__ flags, int E) {
    __shared__ unsigned int h[12544];     // 50176 B
    int bx = blockIdx.x, t = threadIdx.x;
    if (bx < 2 * NBLK) {                  // ---- LDS-privatized histogram ----
        bool isD = bx < NBLK;
        int bb = isD ? bx : bx - NBLK;
        const int* key = isD ? src : dst;
        int nw = isD ? (ND / 2) : (NG / 2);
        for (int i = t; i < nw; i += 256) h[i] = 0;
        __syncthreads();
        int e0 = (int)(((long long)E * bb) / NBLK);
        int e1 = (int)(((long long)E * (bb + 1)) / NBLK);
        for (int e = e0 + t; e < e1; e += 256) {
            int k = key[e];
            atomicAdd(&h[k >> 1], 1u << ((k & 1) * 16));
        }
        __syncthreads();
        unsigned int* po = (unsigned int*)((isD ? partD : partG) + (size_t)bb * (isD ? ND : NG));
        for (int i = t; i < nw; i += 256) po[i] = h[i];
        return;
    }
    int pb = bx - 2 * NBLK;               // ---- prep: convert + swizzle ----
    if (pb < 8) {   // W swizzle: slot=(ntile*4+kc)*64+lane; elem j = W[kc*32+(lane>>4)*8+j][ntile*16+(lane&15)]
        const float* W = wp.w[pb];
        _Float16* o = wsw + (size_t)pb * 16384;
        for (int rep = 0; rep < 8; ++rep) {
            int slot = rep * 256 + t;
            int lane = slot & 63, grp = slot >> 6;
            int kc = grp & 3, ntile = grp >> 2;
            int nn = ntile * 16 + (lane & 15);
            int kb = kc * 32 + (lane >> 4) * 8;
            half8 v;
#pragma unroll
            for (int j = 0; j < 8; ++j) v[j] = (_Float16)W[(size_t)(kb + j) * 128 + nn];
            *(half8*)(o + (size_t)slot * 8) = v;
        }
    } else if (pb == 8 && t < NSB) {      // zero lookback flags for scanall
        flags[t] = 0u;
    }
    const int ndq = ND * 32;
    const int tot = ndq + NG * 32;
    for (int i = pb * 256 + t; i < tot; i += PREPB * 256) {
        const float* x;
        __half* y;
        unsigned char* y8;
        int idx;
        if (i < ndq) { x = xd; y = ydh; y8 = y8d; idx = i; }
        else         { x = xg; y = ygh; y8 = y8g; idx = i - ndq; }
        float4 v = ((const float4*)x)[idx];
        ((__half2*)y)[idx * 2 + 0] = __floats2half2_rn(v.x, v.y);
        ((__half2*)y)[idx * 2 + 1] = __floats2half2_rn(v.z, v.w);
        int p8 = __builtin_amdgcn_cvt_pk_fp8_f32(v.x, v.y, 0, false);
        p8 = __builtin_amdgcn_cvt_pk_fp8_f32(v.z, v.w, p8, true);
        ((int*)y8)[idx] = p8;
    }
}

// ---------------- dispatch 2: fused column-scan + row-ptr scan (decoupled lookback) --------------
__global__ __launch_bounds__(256) void scanall(unsigned short* __restrict__ partD,
                                               unsigned short* __restrict__ partG,
                                               int* __restrict__ row,
                                               unsigned int* __restrict__ flags, int E) {
    __shared__ int sd[256];
    __shared__ int sbase;
    int t = threadIdx.x, bid = blockIdx.x;
    int k = bid * 256 + t;
    int run = 0;
    if (k < NTOT) {                       // per-key scan over NBLK partial slices
        unsigned short* part;
        int nb, kk;
        if (k < ND) { part = partD; nb = ND; kk = k; }
        else        { part = partG; nb = NG; kk = k - ND; }
#pragma unroll 8
        for (int b = 0; b < NBLK; ++b) {
            size_t idx = (size_t)b * nb + kk;
            int v = part[idx];
            part[idx] = (unsigned short)run;
            run += v;
        }
    }
    int tsum = run;                       // this key's total degree
    sd[t] = tsum;
    __syncthreads();
    for (int off = 1; off < 256; off <<= 1) {   // block inclusive scan
        int x = (t >= off) ? sd[t - off] : 0;
        __syncthreads();
        sd[t] += x;
        __syncthreads();
    }
    if (t == 0) {                         // publish block aggregate (+1 so 0 == not-ready)
        unsigned int agg = (unsigned int)sd[255] + 1u;
        __hip_atomic_store(&flags[bid], agg, __ATOMIC_RELEASE, __HIP_MEMORY_SCOPE_AGENT);
    }
    if (t < 64) {                         // parallel lookback: sum ALL predecessor aggregates
        int s = 0;
        for (int i = t; i < bid; i += 64) {
            unsigned int v;
            do {
                v = __hip_atomic_load(&flags[i], __ATOMIC_ACQUIRE, __HIP_MEMORY_SCOPE_AGENT);
            } while (v == 0u);
            s += (int)v - 1;
        }
#pragma unroll
        for (int off = 1; off < 64; off <<= 1) s += __shfl_xor(s, off, 64);
        if (t == 0) sbase = s;
    }
    __syncthreads();
    int base = sbase;
    if (k < NTOT) row[k] = base + sd[t] - tsum;   // global exclusive prefix
    if (bid == 0 && t == 0) row[NTOT] = 2 * E;    // total is static
}

// ---------------- dispatch 3: XCD-write-local CSR fill -------------------------------------------
// Grid = NBLK slices x 8 ranges; bid&7 = range id = XCD (round-robin block->XCD).
// Ranges: x<4 -> disease [x*DRNG,(x+1)*DRNG), x>=4 -> gene [(x-4)*GRNG, ...).
// Each block reads its edge slice, keeps keys in its range, writes col via LDS cursors.
// Col writes from XCD x land in one ~500KB contiguous region -> L2-private, no HBM
// partial-line bouncing (round-4 measured 111 MB HBM writes for this 4 MB array).
__global__ __launch_bounds__(256) void fill2x(const int* __restrict__ src,
                                              const int* __restrict__ dst,
                                              const int* __restrict__ row,
                                              const unsigned short* __restrict__ partD,
                                              const unsigned short* __restrict__ partG,
                                              unsigned short* __restrict__ col, int E) {
    __shared__ unsigned int cur[DRNG];    // 25000 B (max of DRNG, GRNG)
    int t = threadIdx.x, bid = blockIdx.x;
    int x = bid & 7;                      // range / XCD id
    int s = bid >> 3;                     // edge slice 0..NBLK-1
    bool isD = x < 4;
    int r0, rng, nbase, nb;
    const int *key, *val;
    const unsigned short* part;
    if (isD) { r0 = x * DRNG;       rng = DRNG; key = src; val = dst; part = partD; nb = ND; nbase = 0;  }
    else     { r0 = (x - 4) * GRNG; rng = GRNG; key = dst; val = src; part = partG; nb = NG; nbase = ND; }
    for (int i = t; i < rng; i += 256)
        cur[i] = (unsigned int)row[nbase + r0 + i] + part[(size_t)s * nb + r0 + i];
    __syncthreads();
    int e0 = (int)(((long long)E * s) / NBLK);
    int e1 = (int)(((long long)E * (s + 1)) / NBLK);
    for (int e = e0 + t; e < e1; e += 256) {
        int k = key[e];
        if (k >= r0 && k < r0 + rng) {
            unsigned int p = atomicAdd(&cur[k - r0], 1u);
            col[p] = (unsigned short)val[e];
        }
    }
}

// ---------------- dispatches 4/6: fp8 mean aggregation, range-aligned XCD pinning ----------------
// 1 wave per node. XCD x<4: disease range [x*DRNG,...) gathering from gene table (2.56 MB);
// XCD x>=4: gene range gathering from disease table (3.2 MB). Ranges match fill2x so col
// reads and mean-writes are L2-local; gather table stays L2-resident per 4-XCD group.
__global__ __launch_bounds__(256, 8) void agg8m(const unsigned char* __restrict__ Xg,
                                                const unsigned char* __restrict__ Xd,
                                                const int* __restrict__ row,
                                                const unsigned short* __restrict__ col,
                                                __half* __restrict__ outd,
                                                __half* __restrict__ outg) {
    int wid = threadIdx.x >> 6, lane = threadIdx.x & 63;
    int bid = blockIdx.x;
    int xcd = bid & 7, slot = bid >> 3;
    const unsigned char* X;
    _Float16* out;
    int node, nloc;
    if (xcd < 4) {                        // disease range on XCD xcd
        int loc = slot * 4 + wid;
        if (loc >= DRNG) return;
        nloc = xcd * DRNG + loc;
        if (nloc >= ND) return;
        node = nloc;
        X = Xg; out = (_Float16*)outd;
    } else {                              // gene range on XCD xcd
        int loc = slot * 4 + wid;
        if (loc >= GRNG) return;
        nloc = (xcd - 4) * GRNG + loc;
        if (nloc >= NG) return;
        node = ND + nloc;
        X = Xd; out = (_Float16*)outg;
    }
    int b = row[node], e = row[node + 1];
    int g = lane >> 3, f = lane & 7;
    float acc[16];
#pragma unroll
    for (int k = 0; k < 16; ++k) acc[k] = 0.f;
    int j = b + g;
    for (; j + 8 < e; j += 16) {
        int c0 = col[j], c1 = col[j + 8];
        int4 w0 = *(const int4*)(X + (size_t)c0 * 128 + f * 16);
        int4 w1 = *(const int4*)(X + (size_t)c1 * 128 + f * 16);
        const int* wa = (const int*)&w0;
        const int* wb = (const int*)&w1;
#pragma unroll
        for (int q = 0; q < 4; ++q) {
            f32x2 l0 = __builtin_amdgcn_cvt_pk_f32_fp8(wa[q], false);
            f32x2 h0 = __builtin_amdgcn_cvt_pk_f32_fp8(wa[q], true);
            f32x2 l1 = __builtin_amdgcn_cvt_pk_f32_fp8(wb[q], false);
            f32x2 h1 = __builtin_amdgcn_cvt_pk_f32_fp8(wb[q], true);
            acc[q * 4 + 0] += l0[0] + l1[0];
            acc[q * 4 + 1] += l0[1] + l1[1];
            acc[q * 4 + 2] += h0[0] + h1[0];
            acc[q * 4 + 3] += h0[1] + h1[1];
        }
    }
    if (j < e) {
        int c = col[j];
        int4 w = *(const int4*)(X + (size_t)c * 128 + f * 16);
        const int* wa = (const int*)&w;
#pragma unroll
        for (int q = 0; q < 4; ++q) {
            f32x2 l = __builtin_amdgcn_cvt_pk_f32_fp8(wa[q], false);
            f32x2 h = __builtin_amdgcn_cvt_pk_f32_fp8(wa[q], true);
            acc[q * 4 + 0] += l[0];
            acc[q * 4 + 1] += l[1];
            acc[q * 4 + 2] += h[0];
            acc[q * 4 + 3] += h[1];
        }
    }
#pragma unroll
    for (int k = 0; k < 16; ++k) {
        acc[k] += __shfl_xor(acc[k], 8, 64);
        acc[k] += __shfl_xor(acc[k], 16, 64);
        acc[k] += __shfl_xor(acc[k], 32, 64);
    }
    if (g == 0) {
        int deg = e - b;
        float r = 1.0f / (float)(deg > 0 ? deg : 1);
        half8 o0, o1;
#pragma unroll
        for (int k = 0; k < 8; ++k) o0[k] = (_Float16)(acc[k] * r);
#pragma unroll
        for (int k = 0; k < 8; ++k) o1[k] = (_Float16)(acc[8 + k] * r);
        _Float16* op = out + (size_t)nloc * 128 + f * 16;
        *(half8*)op = o0;
        *(half8*)(op + 8) = o1;
    }
}

// ---------------- dispatches 5/7: merged MFMA dual GEMM ------------------------------------------
struct GemmDual {
    const __half *A1d, *A2d, *A1g, *A2g;
    const _Float16 *W1d, *W2d, *W1g, *W2g;
    const float *biasd, *biasg;
    float *Yfd, *Yfg;
    __half *Yhd, *Yhg;
    unsigned char *Y8d, *Y8g;
};
__global__ __launch_bounds__(256) void gemm2(GemmDual p, int nblkD, int layer) {
    int bx = blockIdx.x;
    bool isD = bx < nblkD;
    const __half* A1 = isD ? p.A1d : p.A1g;
    const __half* A2 = isD ? p.A2d : p.A2g;
    const _Float16* W1 = isD ? p.W1d : p.W1g;
    const _Float16* W2 = isD ? p.W2d : p.W2g;
    const float* bias = isD ? p.biasd : p.biasg;
    float* Yf = isD ? p.Yfd : p.Yfg;
    __half* Yh = isD ? p.Yhd : p.Yhg;
    unsigned char* Y8 = isD ? p.Y8d : p.Y8g;
    int n = isD ? ND : NG, b0 = isD ? bx : bx - nblkD;
    int t = threadIdx.x;
    int wave = t >> 6, lane = t & 63;
    int row0 = b0 * 64 + wave * 16;
    if (row0 >= n) return;
    int m = lane & 15, quad = lane >> 4;
    int arow = row0 + m;
    if (arow >= n) arow = n - 1;
    const _Float16* a1p = (const _Float16*)A1 + (size_t)arow * 128 + quad * 8;
    const _Float16* a2p = (const _Float16*)A2 + (size_t)arow * 128 + quad * 8;
    half8 a1[4], a2[4];
#pragma unroll
    for (int kc = 0; kc < 4; ++kc) {
        a1[kc] = *(const half8*)(a1p + kc * 32);
        a2[kc] = *(const half8*)(a2p + kc * 32);
    }
#pragma unroll
    for (int ntile = 0; ntile < 8; ++ntile) {
        f32x4 acc = {0.f, 0.f, 0.f, 0.f};
#pragma unroll
        for (int kc = 0; kc < 4; ++kc) {
            half8 b1 = *(const half8*)(W1 + (size_t)((ntile * 4 + kc) * 64 + lane) * 8);
            acc = __builtin_amdgcn_mfma_f32_16x16x32_f16(a1[kc], b1, acc, 0, 0, 0);
            half8 b2 = *(const half8*)(W2 + (size_t)((ntile * 4 + kc) * 64 + lane) * 8);
            acc = __builtin_amdgcn_mfma_f32_16x16x32_f16(a2[kc], b2, acc, 0, 0, 0);
        }
        int colx = ntile * 16 + m;
        float bb = bias[colx];
#pragma unroll
        for (int r = 0; r < 4; ++r) {
            int rr = row0 + quad * 4 + r;
            if (rr < n) {
                float v = acc[r] + bb;
                if (layer == 2) {
                    Yf[(size_t)rr * 128 + colx] = v;
                } else {
                    Yh[(size_t)rr * 128 + colx] = __float2half(v);
                    int p8 = __builtin_amdgcn_cvt_pk_fp8_f32(v, v, 0, false);
                    Y8[(size_t)rr * 128 + colx] = (unsigned char)(p8 & 0xff);
                }
            }
        }
    }
}

extern "C" void kernel_launch(void* const* d_in, const int* in_sizes, int n_in,
                              void* d_out, int out_size, void* d_ws, size_t ws_size,
                              hipStream_t stream) {
    const float* x_d = (const float*)d_in[0];
    const float* x_g = (const float*)d_in[1];
    const int*   src = (const int*)d_in[2];
    const int*   dst = (const int*)d_in[3];
    float* out = (float*)d_out;

    char* ws = (char*)d_ws;
    unsigned int*   flags = (unsigned int*)(ws + OFF_CNT);
    int*            row   = (int*)(ws + OFF_ROW);
    unsigned short* partD = (unsigned short*)(ws + OFF_PARTD);
    unsigned short* partG = (unsigned short*)(ws + OFF_PARTG);
    unsigned short* col   = (unsigned short*)(ws + OFF_COL);
    _Float16*       wsw   = (_Float16*)(ws + OFF_WSW);
    __half*         xd_h  = (__half*)(ws + OFF_XDH);
    __half*         xg_h  = (__half*)(ws + OFF_XGH);
    unsigned char*  x8d   = (unsigned char*)(ws + OFF_X8D);
    unsigned char*  x8g   = (unsigned char*)(ws + OFF_X8G);
    __half*         md_h  = (__half*)(ws + OFF_MDH);
    __half*         mg_h  = (__half*)(ws + OFF_MGH);
    __half*         d1_h  = (__half*)(ws + OFF_D1H);
    __half*         g1_h  = (__half*)(ws + OFF_G1H);
    unsigned char*  d1_8  = (unsigned char*)(ws + OFF_D18);
    unsigned char*  g1_8  = (unsigned char*)(ws + OFF_G18);

    const int E = in_sizes[2];              // 1,000,000
    const int nblkD = (ND + 63) / 64;       // 391
    const int nblkG = (NG + 63) / 64;       // 313

    WPtrs wp;
    wp.w[0] = (const float*)d_in[4];   // w1_dg_l
    wp.w[1] = (const float*)d_in[6];   // w1_dg_r
    wp.w[2] = (const float*)d_in[7];   // w1_gd_l
    wp.w[3] = (const float*)d_in[9];   // w1_gd_r
    wp.w[4] = (const float*)d_in[10];  // w2_dg_l
    wp.w[5] = (const float*)d_in[12];  // w2_dg_r
    wp.w[6] = (const float*)d_in[13];  // w2_gd_l
    wp.w[7] = (const float*)d_in[15];  // w2_gd_r
    const float* b1_dg = (const float*)d_in[5];
    const float* b1_gd = (const float*)d_in[8];
    const float* b2_dg = (const float*)d_in[11];
    const float* b2_gd = (const float*)d_in[14];

    // 1. hist + prep (independent, disjoint block ranges) + flag zeroing
    prep_hist<<<2 * NBLK + PREPB, 256, 0, stream>>>(x_d, x_g, xd_h, xg_h, x8d, x8g,
                                                    wp, wsw, src, dst, partD, partG, flags, E);
    // 2. fused scan -> rowptr (decoupled lookback)
    scanall<<<NSB, 256, 0, stream>>>(partD, partG, row, flags, E);
    // 3. XCD-write-local CSR fill
    fill2x<<<NBLK * 8, 256, 0, stream>>>(src, dst, row, partD, partG, col, E);

    // 4-5. layer 1
    agg8m<<<AGG_GRID, 256, 0, stream>>>(x8g, x8d, row, col, md_h, mg_h);
    GemmDual g1p;
    g1p.A1d = md_h; g1p.A2d = xd_h; g1p.W1d = wsw + 2 * 16384; g1p.W2d = wsw + 3 * 16384;
    g1p.biasd = b1_gd; g1p.Yfd = nullptr; g1p.Yhd = d1_h; g1p.Y8d = d1_8;
    g1p.A1g = mg_h; g1p.A2g = xg_h; g1p.W1g = wsw + 0 * 16384; g1p.W2g = wsw + 1 * 16384;
    g1p.biasg = b1_dg; g1p.Yfg = nullptr; g1p.Yhg = g1_h; g1p.Y8g = g1_8;
    gemm2<<<nblkD + nblkG, 256, 0, stream>>>(g1p, nblkD, 1);

    // 6-7. layer 2
    agg8m<<<AGG_GRID, 256, 0, stream>>>(g1_8, d1_8, row, col, md_h, mg_h);
    GemmDual g2p;
    g2p.A1d = md_h; g2p.A2d = d1_h; g2p.W1d = wsw + 6 * 16384; g2p.W2d = wsw + 7 * 16384;
    g2p.biasd = b2_gd; g2p.Yfd = out; g2p.Yhd = nullptr; g2p.Y8d = nullptr;
    g2p.A1g = mg_h; g2p.A2g = g1_h; g2p.W1g = wsw + 4 * 16384; g2p.W2g = wsw + 5 * 16384;
    g2p.biasg = b2_dg; g2p.Yfg = out + (size_t)ND * 128; g2p.Yhg = nullptr; g2p.Y8g = nullptr;
    gemm2<<<nblkD + nblkG, 256, 0, stream>>>(g2p, nblkD, 2);
}